// Round 19
// baseline (181.222 us; speedup 1.0000x reference)
//
#include <hip/hip_runtime.h>
#include <hip/hip_bf16.h>

typedef __attribute__((ext_vector_type(8))) short bf16x8;
typedef __attribute__((ext_vector_type(4))) float f32x4;
typedef __attribute__((ext_vector_type(16))) float f32x16;
typedef __attribute__((ext_vector_type(4))) unsigned uint4v;

#define MFMA16(a, b, c) __builtin_amdgcn_mfma_f32_16x16x32_bf16(a, b, c, 0, 0, 0)
#define MFMA32(a, b, c) __builtin_amdgcn_mfma_f32_32x32x16_bf16(a, b, c, 0, 0, 0)

__device__ __forceinline__ unsigned short f2bfn(float f) {
#if defined(__gfx950__)
  __bf16 h = (__bf16)f;
  return __builtin_bit_cast(unsigned short, h);
#else
  union { float f; unsigned u; } x; x.f = f;
  unsigned r = x.u + 0x7fffu + ((x.u >> 16) & 1u);
  return (unsigned short)(r >> 16);
#endif
}

__device__ __forceinline__ unsigned cvtpk(float lo, float hi) {
  unsigned w;
  asm("v_cvt_pk_bf16_f32 %0, %1, %2" : "=v"(w) : "v"(lo), "v"(hi));
  return w;
}

// ---------------- fp32 -> bf16 conversion ----------------
__device__ __forceinline__ void cvt_range(const float* __restrict__ s,
                                          unsigned short* __restrict__ d,
                                          int i, int st, int n8) {
  for (; i < n8; i += st) {
    const float4* sp = reinterpret_cast<const float4*>(s) + 2 * (size_t)i;
    float4 a = sp[0], b = sp[1];
    uint4v o;
    o[0] = cvtpk(a.x, a.y); o[1] = cvtpk(a.z, a.w);
    o[2] = cvtpk(b.x, b.y); o[3] = cvtpk(b.z, b.w);
    reinterpret_cast<uint4v*>(d)[i] = o;
  }
}

__global__ void cvt1_kernel(const float* __restrict__ s, unsigned short* __restrict__ d, int n8) {
  cvt_range(s, d, blockIdx.x * blockDim.x + threadIdx.x, gridDim.x * blockDim.x, n8);
}

// y<4: weight matrices; y==4: Q input (larger, grid-strided)
__global__ void cvt_first_kernel(const float* s0, const float* s1, const float* s2,
                                 const float* s3, unsigned short* d0, unsigned short* d1,
                                 unsigned short* d2, unsigned short* d3, int wn8,
                                 const float* sq, unsigned short* dq, int qn8) {
  const float* s; unsigned short* d; int n8;
  switch (blockIdx.y) {
    case 0: s = s0; d = d0; n8 = wn8; break;
    case 1: s = s1; d = d1; n8 = wn8; break;
    case 2: s = s2; d = d2; n8 = wn8; break;
    case 3: s = s3; d = d3; n8 = wn8; break;
    default: s = sq; d = dq; n8 = qn8; break;
  }
  cvt_range(s, d, blockIdx.x * blockDim.x + threadIdx.x, gridDim.x * blockDim.x, n8);
}

// ---------------- GEMM: BK=32, 3-buffer counted-vmcnt pipeline (r18 shape) ----------------
// 1D grid: n = sx & (2^nshift-1), m = sx >> nshift; nshift==3 gets the
// XCD-chunk swizzle (4MB working set per XCD). Blocks bx >= ngemm piggyback cvt
// (they exit before any barrier). 48KB LDS -> 3 blocks/CU. Per iter:
// vmcnt(4) [oldest stage retired, next stays in flight] + s_barrier +
// sched_barrier, then stage(t+2), then 16 MFMA. Stage(t+2) targets buffer
// (t-1)%3 whose readers finished before this barrier -> race-free.
// MODE 0: bias[col], out bf16 scattered [B,H,S,64], *oscale
// MODE 1: bias[col], out fp32 row-major [M,N]
// MODE 2: bias[row], out bf16 V^T [BH,64,S]
template <int MODE>
__global__ __launch_bounds__(256) void gemm_kernel(
    const unsigned short* __restrict__ Av, const unsigned short* __restrict__ Bv,
    const float* __restrict__ bias, void* __restrict__ outv,
    int M, int N, int K, float oscale, int nshift, int ngemm,
    const float* __restrict__ csrc, unsigned short* __restrict__ cdst, int cn8) {
  constexpr int BM = 128, BN = 128, BK = 32;
  __shared__ __align__(16) unsigned short As[3][BM * BK];
  __shared__ __align__(16) unsigned short Bs[3][BN * BK];
  const int bx = blockIdx.x;
  const int tid = threadIdx.x;
  if (bx >= ngemm) {
    cvt_range(csrc, cdst, (bx - ngemm) * blockDim.x + tid,
              (gridDim.x - ngemm) * blockDim.x, cn8);
    return;
  }
  int sx = bx;
  if (nshift == 3) sx = (bx & 7) * (ngemm >> 3) + (bx >> 3);
  const int lane = tid & 63, wave = tid >> 6;
  const int wr = wave >> 1, wc = wave & 1;
  const int m0 = (sx >> nshift) * BM, n0 = (sx & ((1 << nshift) - 1)) * BN;
  const int rb = lane & 15, g = lane >> 4;
  // BK=32 bank mapping (r10-verified): source pre-swizzle over 4 chunks/row,
  // row key (r>>1)&3; read chunk g ^ rk.
  const int swz = ((lane & 3) ^ ((lane >> 3) & 3)) * 8;
  const int rk = (rb >> 1) & 3;
  f32x4 acc[4][4] = {};

  const unsigned short* Ab = Av + (size_t)m0 * K;
  const unsigned short* Bb = Bv + (size_t)n0 * K;

  auto stage = [&](int buf, int k0) {
#pragma unroll
    for (int i = 0; i < 2; ++i) {
      const int c = wave * 128 + i * 64 + lane;  // 16B chunk, linear LDS
      const int r = c >> 2;                      // tile row (4 chunks/row)
      __builtin_amdgcn_global_load_lds(
          (const __attribute__((address_space(1))) unsigned int*)(Ab + (size_t)r * K + k0 + swz),
          (__attribute__((address_space(3))) unsigned int*)&As[buf][c * 8], 16, 0, 0);
      __builtin_amdgcn_global_load_lds(
          (const __attribute__((address_space(1))) unsigned int*)(Bb + (size_t)r * K + k0 + swz),
          (__attribute__((address_space(3))) unsigned int*)&Bs[buf][c * 8], 16, 0, 0);
    }
  };

  const int nt = K / BK;  // 32
  stage(0, 0);
  stage(1, BK);
  for (int t = 0; t < nt; ++t) {
    if (t < nt - 1) asm volatile("s_waitcnt vmcnt(4)" ::: "memory");
    else            asm volatile("s_waitcnt vmcnt(0)" ::: "memory");
    __builtin_amdgcn_s_barrier();
    __builtin_amdgcn_sched_barrier(0);
    if (t + 2 < nt) stage((t + 2) % 3, (t + 2) * BK);
    const unsigned short* A_ = As[t % 3];
    const unsigned short* B_ = Bs[t % 3];
    bf16x8 af[4], bfr[4];
#pragma unroll
    for (int mi = 0; mi < 4; ++mi)
      af[mi] = *reinterpret_cast<const bf16x8*>(
          &A_[(wr * 64 + mi * 16 + rb) * 32 + ((g ^ rk) * 8)]);
#pragma unroll
    for (int ni = 0; ni < 4; ++ni)
      bfr[ni] = *reinterpret_cast<const bf16x8*>(
          &B_[(wc * 64 + ni * 16 + rb) * 32 + ((g ^ rk) * 8)]);
#pragma unroll
    for (int mi = 0; mi < 4; ++mi)
#pragma unroll
      for (int ni = 0; ni < 4; ++ni)
        acc[mi][ni] = MFMA16(af[mi], bfr[ni], acc[mi][ni]);
  }

#pragma unroll
  for (int mi = 0; mi < 4; ++mi) {
#pragma unroll
    for (int ni = 0; ni < 4; ++ni) {
      int col = n0 + wc * 64 + ni * 16 + rb;
      if constexpr (MODE != 2) {
        float bvv = bias[col];
#pragma unroll
        for (int j = 0; j < 4; ++j) {
          int row = m0 + wr * 64 + mi * 16 + g * 4 + j;
          float v = acc[mi][ni][j] + bvv;
          if constexpr (MODE == 0) {
            v *= oscale;
            int b = row >> 11, s = row & 2047;
            int h = col >> 6, e = col & 63;
            ((unsigned short*)outv)[((size_t)(b * 16 + h) * 2048 + s) * 64 + e] = f2bfn(v);
          } else {
            ((float*)outv)[(size_t)row * N + col] = v;
          }
        }
      } else {
        int bb = col >> 11, s = col & 2047;
#pragma unroll
        for (int j = 0; j < 4; ++j) {
          int row = m0 + wr * 64 + mi * 16 + g * 4 + j;
          float v = acc[mi][ni][j] + bias[row];
          int h = row >> 6, e = row & 63;
          ((unsigned short*)outv)[((size_t)(bb * 16 + h) * 64 + e) * 2048 + s] = f2bfn(v);
        }
      }
    }
  }
}

// ---------------- flash attention: T15 double-pipeline (r18 proven) ----------------
__global__ __launch_bounds__(256) void attn9_kernel(
    const unsigned short* __restrict__ Qp, const unsigned short* __restrict__ Kp,
    const unsigned short* __restrict__ Vtp, unsigned short* __restrict__ ctx) {
  constexpr int S = 2048;
  __shared__ __align__(16) unsigned short Ks[3][64 * 64];
  __shared__ __align__(16) unsigned short Vs[3][64 * 64];
  const int bx = blockIdx.x;
  const int bh = bx & 63;
  const int qti = 15 - (bx >> 6);  // heavy tiles first
  const int tid = threadIdx.x, wave = tid >> 6, lane = tid & 63;
  const int l31 = lane & 31, hb = lane >> 5;
  const int x7 = l31 & 7;
  const int qw = qti * 128 + wave * 32;
  const unsigned short* Qb = Qp + (size_t)bh * S * 64;
  const unsigned short* Kb = Kp + (size_t)bh * S * 64;
  const unsigned short* Vb = Vtp + (size_t)bh * 64 * S;

  bf16x8 qg[4];
#pragma unroll
  for (int kc = 0; kc < 4; ++kc)
    qg[kc] = *reinterpret_cast<const bf16x8*>(
        Qb + (size_t)(qw + l31) * 64 + 16 * kc + 8 * hb);

  bf16x8 ones;
#pragma unroll
  for (int i = 0; i < 8; ++i) ones[i] = (short)0x3F80;

  f32x16 ls = {};
  f32x16 o[2] = {};
  const int sswz = ((lane & 7) ^ (lane >> 3)) * 8;
  const int nt = qti * 2 + 2;  // always even

  const int ci0 = wave * 2 * 64 + lane, ci1 = ci0 + 64;
  const int r0 = wave * 16 + (lane >> 3), r1 = r0 + 8;
  const int rs0 = (r0 & 51) | ((r0 & 4) << 1) | ((r0 & 8) >> 1);
  const int rs1 = (r1 & 51) | ((r1 & 4) << 1) | ((r1 & 8) >> 1);
  const unsigned short* ks0 = Kb + (size_t)rs0 * 64 + sswz;
  const unsigned short* ks1 = Kb + (size_t)rs1 * 64 + sswz;
  const unsigned short* vs0 = Vb + (size_t)r0 * S + sswz;
  const unsigned short* vs1 = Vb + (size_t)r1 * S + sswz;

  auto stage = [&](int buf) {
    __builtin_amdgcn_global_load_lds(
        (const __attribute__((address_space(1))) unsigned int*)ks0,
        (__attribute__((address_space(3))) unsigned int*)&Ks[buf][ci0 * 8], 16, 0, 0);
    __builtin_amdgcn_global_load_lds(
        (const __attribute__((address_space(1))) unsigned int*)ks1,
        (__attribute__((address_space(3))) unsigned int*)&Ks[buf][ci1 * 8], 16, 0, 0);
    __builtin_amdgcn_global_load_lds(
        (const __attribute__((address_space(1))) unsigned int*)vs0,
        (__attribute__((address_space(3))) unsigned int*)&Vs[buf][ci0 * 8], 16, 0, 0);
    __builtin_amdgcn_global_load_lds(
        (const __attribute__((address_space(1))) unsigned int*)vs1,
        (__attribute__((address_space(3))) unsigned int*)&Vs[buf][ci1 * 8], 16, 0, 0);
    ks0 += 4096; ks1 += 4096;  // +64 K-rows
    vs0 += 64; vs1 += 64;      // +64 kv-cols
  };

  auto qkt = [&](f32x16* sacc, const unsigned short* K_, int kv0) {
    sacc[0] = f32x16{};
    sacc[1] = f32x16{};
    __builtin_amdgcn_s_setprio(1);
#pragma unroll
    for (int kc = 0; kc < 4; ++kc) {
      bf16x8 kf0 = *reinterpret_cast<const bf16x8*>(
          &K_[l31 * 64 + ((2 * kc + hb) ^ x7) * 8]);
      bf16x8 kf1 = *reinterpret_cast<const bf16x8*>(
          &K_[(32 + l31) * 64 + ((2 * kc + hb) ^ x7) * 8]);
      sacc[0] = MFMA32(kf0, qg[kc], sacc[0]);
      sacc[1] = MFMA32(kf1, qg[kc], sacc[1]);
    }
    __builtin_amdgcn_s_setprio(0);
    if (kv0 + 63 > qw) {
      const int qrel = qw + l31 - kv0 - 8 * hb;
#pragma unroll
      for (int mi = 0; mi < 2; ++mi)
#pragma unroll
        for (int r = 0; r < 16; ++r) {
          int koff = (r & 7) + 16 * (r >> 3) + 32 * mi;
          if (koff > qrel) sacc[mi][r] = -1e30f;
        }
    }
  };

  auto finish = [&](const f32x16* sacc, const unsigned short* V_) {
    unsigned pw[2][8];
#pragma unroll
    for (int mi = 0; mi < 2; ++mi)
#pragma unroll
      for (int i = 0; i < 8; ++i) {
        float pa = __builtin_amdgcn_exp2f(sacc[mi][2 * i]);
        float pb = __builtin_amdgcn_exp2f(sacc[mi][2 * i + 1]);
        pw[mi][i] = cvtpk(pa, pb);
      }
    __builtin_amdgcn_s_setprio(1);
#pragma unroll
    for (int c = 0; c < 4; ++c) {
      union { unsigned u[4]; bf16x8 v; } pu;
      pu.u[0] = pw[c >> 1][(c & 1) * 4 + 0];
      pu.u[1] = pw[c >> 1][(c & 1) * 4 + 1];
      pu.u[2] = pw[c >> 1][(c & 1) * 4 + 2];
      pu.u[3] = pw[c >> 1][(c & 1) * 4 + 3];
#pragma unroll
      for (int db = 0; db < 2; ++db) {
        bf16x8 vf = *reinterpret_cast<const bf16x8*>(
            &V_[(32 * db + l31) * 64 + ((2 * c + hb) ^ x7) * 8]);
        o[db] = MFMA32(vf, pu.v, o[db]);
      }
      ls = MFMA32(ones, pu.v, ls);
    }
    __builtin_amdgcn_s_setprio(0);
  };

  stage(0);
  stage(1);

  f32x16 sA[2], sB[2];

  for (int it = 0; it < nt; it += 2) {
    if (it < nt - 1) asm volatile("s_waitcnt vmcnt(4)" ::: "memory");
    else             asm volatile("s_waitcnt vmcnt(0)" ::: "memory");
    __builtin_amdgcn_s_barrier();
    __builtin_amdgcn_sched_barrier(0);
    {
      const int kv0 = 64 * it;
      if (kv0 <= qw + 31) qkt(sA, Ks[it % 3], kv0);
      if (it > 0 && kv0 - 64 <= qw + 31) finish(sB, Vs[(it - 1) % 3]);
      if (it + 2 < nt) {
        __builtin_amdgcn_s_barrier();
        __builtin_amdgcn_sched_barrier(0);
        stage((it + 2) % 3);
      }
    }
    const int it1 = it + 1;
    if (it1 < nt - 1) asm volatile("s_waitcnt vmcnt(4)" ::: "memory");
    else              asm volatile("s_waitcnt vmcnt(0)" ::: "memory");
    __builtin_amdgcn_s_barrier();
    __builtin_amdgcn_sched_barrier(0);
    {
      const int kv0 = 64 * it1;
      if (kv0 <= qw + 31) qkt(sB, Ks[it1 % 3], kv0);
      if (kv0 - 64 <= qw + 31) finish(sA, Vs[it % 3]);
      if (it1 + 2 < nt) {
        __builtin_amdgcn_s_barrier();
        __builtin_amdgcn_sched_barrier(0);
        stage((it1 + 2) % 3);
      }
    }
  }
  if (64 * (nt - 1) <= qw + 31) finish(sB, Vs[(nt - 1) % 3]);

  const float inv = 1.0f / ls[0];
  const int b = bh >> 4, h = bh & 15;
  const int q = qw + l31;
  unsigned short* cp = ctx + ((size_t)(b * 2048 + q) * 1024) + h * 64;
#pragma unroll
  for (int db = 0; db < 2; ++db)
#pragma unroll
    for (int i = 0; i < 8; ++i) {
      unsigned w = cvtpk(o[db][2 * i] * inv, o[db][2 * i + 1] * inv);
      int d = 32 * db + ((2 * i) & 3) + 8 * (i >> 1) + 4 * hb;
      *reinterpret_cast<unsigned*>(cp + d) = w;
    }
}

extern "C" void kernel_launch(void* const* d_in, const int* in_sizes, int n_in,
                              void* d_out, int out_size, void* d_ws, size_t ws_size,
                              hipStream_t stream) {
  const float* in_q = (const float*)d_in[0];
  const float* in_k = (const float*)d_in[1];
  const float* in_v = (const float*)d_in[2];
  const float* WQw = (const float*)d_in[3];
  const float* WQb = (const float*)d_in[4];
  const float* WKw = (const float*)d_in[5];
  const float* WKb = (const float*)d_in[6];
  const float* WVw = (const float*)d_in[7];
  const float* WVb = (const float*)d_in[8];
  const float* Ww  = (const float*)d_in[9];
  const float* Wb  = (const float*)d_in[10];
  float* out = (float*)d_out;

  constexpr size_t PROJ = (size_t)4 * 16 * 2048 * 64;  // 8,388,608 elems
  constexpr size_t WSZ = (size_t)1024 * 1024;
  const float qscale = 0.03125f * 1.4426950408889634f;  // 1/sqrt(1024) * log2(e)
  unsigned short* wsp = (unsigned short*)d_ws;

  const bool fused = ws_size >= (6 * PROJ + 4 * WSZ) * sizeof(unsigned short);

  if (fused) {
    unsigned short* Qp   = wsp;
    unsigned short* Kp   = wsp + PROJ;
    unsigned short* Vt   = wsp + 2 * PROJ;
    unsigned short* inq  = wsp + 3 * PROJ;  // later aliased as ctx
    unsigned short* ctx  = inq;
    unsigned short* ink  = wsp + 4 * PROJ;
    unsigned short* inv  = wsp + 5 * PROJ;
    unsigned short* wq16 = wsp + 6 * PROJ;
    unsigned short* wk16 = wq16 + WSZ;
    unsigned short* wv16 = wk16 + WSZ;
    unsigned short* ww16 = wv16 + WSZ;

    cvt_first_kernel<<<dim3(1024, 5), 256, 0, stream>>>(
        WQw, WKw, WVw, Ww, wq16, wk16, wv16, ww16, (int)(WSZ / 8),
        in_q, inq, (int)(PROJ / 8));
    gemm_kernel<0><<<2560, 256, 0, stream>>>(inq, wq16, WQb, Qp, 8192, 1024, 1024,
                                             qscale, 3, 512, in_k, ink, (int)(PROJ / 8));
    gemm_kernel<0><<<2560, 256, 0, stream>>>(ink, wk16, WKb, Kp, 8192, 1024, 1024,
                                             1.0f, 3, 512, in_v, inv, (int)(PROJ / 8));
    gemm_kernel<2><<<512, 256, 0, stream>>>(wv16, inv, WVb, Vt, 1024, 8192, 1024,
                                            1.0f, 6, 512, nullptr, nullptr, 0);
    attn9_kernel<<<1024, 256, 0, stream>>>(Qp, Kp, Vt, ctx);
    gemm_kernel<1><<<512, 256, 0, stream>>>(ctx, ww16, Wb, out, 8192, 1024, 1024,
                                            1.0f, 3, 512, nullptr, nullptr, 0);
  } else {
    unsigned short* Qp   = wsp;
    unsigned short* Kp   = wsp + PROJ;
    unsigned short* Vt   = wsp + 2 * PROJ;
    unsigned short* in16 = wsp + 3 * PROJ;
    unsigned short* ctx  = in16;
    unsigned short* wq16 = wsp + 4 * PROJ;
    unsigned short* wk16 = wq16 + WSZ;
    unsigned short* wv16 = wk16 + WSZ;
    unsigned short* ww16 = wv16 + WSZ;

    cvt_first_kernel<<<dim3(1024, 5), 256, 0, stream>>>(
        WQw, WKw, WVw, Ww, wq16, wk16, wv16, ww16, (int)(WSZ / 8),
        in_q, in16, (int)(PROJ / 8));
    gemm_kernel<0><<<512, 256, 0, stream>>>(in16, wq16, WQb, Qp, 8192, 1024, 1024,
                                            qscale, 3, 512, nullptr, nullptr, 0);
    cvt1_kernel<<<2048, 256, 0, stream>>>(in_k, in16, (int)(PROJ / 8));
    gemm_kernel<0><<<512, 256, 0, stream>>>(in16, wk16, WKb, Kp, 8192, 1024, 1024,
                                            1.0f, 3, 512, nullptr, nullptr, 0);
    cvt1_kernel<<<2048, 256, 0, stream>>>(in_v, in16, (int)(PROJ / 8));
    gemm_kernel<2><<<512, 256, 0, stream>>>(wv16, in16, WVb, Vt, 1024, 8192, 1024,
                                            1.0f, 6, 512, nullptr, nullptr, 0);
    attn9_kernel<<<1024, 256, 0, stream>>>(Qp, Kp, Vt, ctx);
    gemm_kernel<1><<<512, 256, 0, stream>>>(ctx, ww16, Wb, out, 8192, 1024, 1024,
                                            1.0f, 3, 512, nullptr, nullptr, 0);
  }
}

// Round 20
// 170.358 us; speedup vs baseline: 1.0638x; 1.0638x over previous
//
#include <hip/hip_runtime.h>
#include <hip/hip_bf16.h>

typedef __attribute__((ext_vector_type(8))) short bf16x8;
typedef __attribute__((ext_vector_type(4))) float f32x4;
typedef __attribute__((ext_vector_type(16))) float f32x16;
typedef __attribute__((ext_vector_type(4))) unsigned uint4v;

#define MFMA16(a, b, c) __builtin_amdgcn_mfma_f32_16x16x32_bf16(a, b, c, 0, 0, 0)
#define MFMA32(a, b, c) __builtin_amdgcn_mfma_f32_32x32x16_bf16(a, b, c, 0, 0, 0)

__device__ __forceinline__ unsigned short f2bfn(float f) {
#if defined(__gfx950__)
  __bf16 h = (__bf16)f;
  return __builtin_bit_cast(unsigned short, h);
#else
  union { float f; unsigned u; } x; x.f = f;
  unsigned r = x.u + 0x7fffu + ((x.u >> 16) & 1u);
  return (unsigned short)(r >> 16);
#endif
}

__device__ __forceinline__ unsigned cvtpk(float lo, float hi) {
  unsigned w;
  asm("v_cvt_pk_bf16_f32 %0, %1, %2" : "=v"(w) : "v"(lo), "v"(hi));
  return w;
}

// ---------------- fp32 -> bf16 conversion ----------------
__device__ __forceinline__ void cvt_range(const float* __restrict__ s,
                                          unsigned short* __restrict__ d,
                                          int i, int st, int n8) {
  for (; i < n8; i += st) {
    const float4* sp = reinterpret_cast<const float4*>(s) + 2 * (size_t)i;
    float4 a = sp[0], b = sp[1];
    uint4v o;
    o[0] = cvtpk(a.x, a.y); o[1] = cvtpk(a.z, a.w);
    o[2] = cvtpk(b.x, b.y); o[3] = cvtpk(b.z, b.w);
    reinterpret_cast<uint4v*>(d)[i] = o;
  }
}

__global__ void cvt1_kernel(const float* __restrict__ s, unsigned short* __restrict__ d, int n8) {
  cvt_range(s, d, blockIdx.x * blockDim.x + threadIdx.x, gridDim.x * blockDim.x, n8);
}

// y<4: weight matrices; y==4: Q input (larger, grid-strided)
__global__ void cvt_first_kernel(const float* s0, const float* s1, const float* s2,
                                 const float* s3, unsigned short* d0, unsigned short* d1,
                                 unsigned short* d2, unsigned short* d3, int wn8,
                                 const float* sq, unsigned short* dq, int qn8) {
  const float* s; unsigned short* d; int n8;
  switch (blockIdx.y) {
    case 0: s = s0; d = d0; n8 = wn8; break;
    case 1: s = s1; d = d1; n8 = wn8; break;
    case 2: s = s2; d = d2; n8 = wn8; break;
    case 3: s = s3; d = d3; n8 = wn8; break;
    default: s = sq; d = dq; n8 = qn8; break;
  }
  cvt_range(s, d, blockIdx.x * blockDim.x + threadIdx.x, gridDim.x * blockDim.x, n8);
}

// ---------------- GEMM (proven BK=64 config) ----------------
// 1D grid: n = sx & (2^nshift-1), m = sx >> nshift; nshift==3 gets the
// XCD-chunk swizzle (4MB working set per XCD). Blocks bx >= ngemm piggyback cvt.
// MODE 0: bias[col], out bf16 scattered [B,H,S,64], *oscale
// MODE 1: bias[col], out fp32 row-major [M,N]
// MODE 2: bias[row], out bf16 V^T [BH,64,S]
template <int MODE>
__global__ __launch_bounds__(256) void gemm_kernel(
    const unsigned short* __restrict__ Av, const unsigned short* __restrict__ Bv,
    const float* __restrict__ bias, void* __restrict__ outv,
    int M, int N, int K, float oscale, int nshift, int ngemm,
    const float* __restrict__ csrc, unsigned short* __restrict__ cdst, int cn8) {
  constexpr int BM = 128, BN = 128, BK = 64;
  __shared__ __align__(16) unsigned short As[2][BM * BK];
  __shared__ __align__(16) unsigned short Bs[2][BN * BK];
  const int bx = blockIdx.x;
  const int tid = threadIdx.x;
  if (bx >= ngemm) {
    cvt_range(csrc, cdst, (bx - ngemm) * blockDim.x + tid,
              (gridDim.x - ngemm) * blockDim.x, cn8);
    return;
  }
  int sx = bx;
  if (nshift == 3) sx = (bx & 7) * (ngemm >> 3) + (bx >> 3);
  const int lane = tid & 63, wave = tid >> 6;
  const int wr = wave >> 1, wc = wave & 1;
  const int m0 = (sx >> nshift) * BM, n0 = (sx & ((1 << nshift) - 1)) * BN;
  const int rb = lane & 15, g = lane >> 4;
  const int swz = ((lane & 7) ^ ((lane >> 3) & 7)) * 8;
  f32x4 acc[4][4] = {};

  const unsigned short* Ab = Av + (size_t)m0 * K;
  const unsigned short* Bb = Bv + (size_t)n0 * K;

  auto stage = [&](int buf, int k0) {
#pragma unroll
    for (int i = 0; i < 4; ++i) {
      const int c = wave * 256 + i * 64 + lane;
      const int r = c >> 3;
      __builtin_amdgcn_global_load_lds(
          (const __attribute__((address_space(1))) unsigned int*)(Ab + (size_t)r * K + k0 + swz),
          (__attribute__((address_space(3))) unsigned int*)&As[buf][c * 8], 16, 0, 0);
      __builtin_amdgcn_global_load_lds(
          (const __attribute__((address_space(1))) unsigned int*)(Bb + (size_t)r * K + k0 + swz),
          (__attribute__((address_space(3))) unsigned int*)&Bs[buf][c * 8], 16, 0, 0);
    }
  };

  const int nt = K / BK;
  stage(0, 0);
  int cur = 0;
  for (int t = 0; t < nt; ++t) {
    __syncthreads();
    if (t + 1 < nt) stage(cur ^ 1, (t + 1) * BK);
    const unsigned short* A_ = As[cur];
    const unsigned short* B_ = Bs[cur];
#pragma unroll
    for (int kc = 0; kc < 2; ++kc) {
      bf16x8 af[4], bfr[4];
#pragma unroll
      for (int mi = 0; mi < 4; ++mi)
        af[mi] = *reinterpret_cast<const bf16x8*>(
            &A_[(wr * 64 + mi * 16 + rb) * 64 + (((kc * 4 + g) ^ (rb & 7)) * 8)]);
#pragma unroll
      for (int ni = 0; ni < 4; ++ni)
        bfr[ni] = *reinterpret_cast<const bf16x8*>(
            &B_[(wc * 64 + ni * 16 + rb) * 64 + (((kc * 4 + g) ^ (rb & 7)) * 8)]);
#pragma unroll
      for (int mi = 0; mi < 4; ++mi)
#pragma unroll
        for (int ni = 0; ni < 4; ++ni)
          acc[mi][ni] = MFMA16(af[mi], bfr[ni], acc[mi][ni]);
    }
    cur ^= 1;
  }

#pragma unroll
  for (int mi = 0; mi < 4; ++mi) {
#pragma unroll
    for (int ni = 0; ni < 4; ++ni) {
      int col = n0 + wc * 64 + ni * 16 + rb;
      if constexpr (MODE != 2) {
        float bvv = bias[col];
#pragma unroll
        for (int j = 0; j < 4; ++j) {
          int row = m0 + wr * 64 + mi * 16 + g * 4 + j;
          float v = acc[mi][ni][j] + bvv;
          if constexpr (MODE == 0) {
            v *= oscale;
            int b = row >> 11, s = row & 2047;
            int h = col >> 6, e = col & 63;
            ((unsigned short*)outv)[((size_t)(b * 16 + h) * 2048 + s) * 64 + e] = f2bfn(v);
          } else {
            ((float*)outv)[(size_t)row * N + col] = v;
          }
        }
      } else {
        int bb = col >> 11, s = col & 2047;
#pragma unroll
        for (int j = 0; j < 4; ++j) {
          int row = m0 + wr * 64 + mi * 16 + g * 4 + j;
          float v = acc[mi][ni][j] + bias[row];
          int h = row >> 6, e = row & 63;
          ((unsigned short*)outv)[((size_t)(bb * 16 + h) * 64 + e) * 2048 + s] = f2bfn(v);
        }
      }
    }
  }
}

// ---------------- flash attention: T15 double-pipeline (r18 proven) ----------------
__global__ __launch_bounds__(256) void attn9_kernel(
    const unsigned short* __restrict__ Qp, const unsigned short* __restrict__ Kp,
    const unsigned short* __restrict__ Vtp, unsigned short* __restrict__ ctx) {
  constexpr int S = 2048;
  __shared__ __align__(16) unsigned short Ks[3][64 * 64];
  __shared__ __align__(16) unsigned short Vs[3][64 * 64];
  const int bx = blockIdx.x;
  const int bh = bx & 63;
  const int qti = 15 - (bx >> 6);  // heavy tiles first
  const int tid = threadIdx.x, wave = tid >> 6, lane = tid & 63;
  const int l31 = lane & 31, hb = lane >> 5;
  const int x7 = l31 & 7;
  const int qw = qti * 128 + wave * 32;
  const unsigned short* Qb = Qp + (size_t)bh * S * 64;
  const unsigned short* Kb = Kp + (size_t)bh * S * 64;
  const unsigned short* Vb = Vtp + (size_t)bh * 64 * S;

  bf16x8 qg[4];
#pragma unroll
  for (int kc = 0; kc < 4; ++kc)
    qg[kc] = *reinterpret_cast<const bf16x8*>(
        Qb + (size_t)(qw + l31) * 64 + 16 * kc + 8 * hb);

  bf16x8 ones;
#pragma unroll
  for (int i = 0; i < 8; ++i) ones[i] = (short)0x3F80;

  f32x16 ls = {};
  f32x16 o[2] = {};
  const int sswz = ((lane & 7) ^ (lane >> 3)) * 8;
  const int nt = qti * 2 + 2;  // always even

  const int ci0 = wave * 2 * 64 + lane, ci1 = ci0 + 64;
  const int r0 = wave * 16 + (lane >> 3), r1 = r0 + 8;
  const int rs0 = (r0 & 51) | ((r0 & 4) << 1) | ((r0 & 8) >> 1);
  const int rs1 = (r1 & 51) | ((r1 & 4) << 1) | ((r1 & 8) >> 1);
  const unsigned short* ks0 = Kb + (size_t)rs0 * 64 + sswz;
  const unsigned short* ks1 = Kb + (size_t)rs1 * 64 + sswz;
  const unsigned short* vs0 = Vb + (size_t)r0 * S + sswz;
  const unsigned short* vs1 = Vb + (size_t)r1 * S + sswz;

  auto stage = [&](int buf) {
    __builtin_amdgcn_global_load_lds(
        (const __attribute__((address_space(1))) unsigned int*)ks0,
        (__attribute__((address_space(3))) unsigned int*)&Ks[buf][ci0 * 8], 16, 0, 0);
    __builtin_amdgcn_global_load_lds(
        (const __attribute__((address_space(1))) unsigned int*)ks1,
        (__attribute__((address_space(3))) unsigned int*)&Ks[buf][ci1 * 8], 16, 0, 0);
    __builtin_amdgcn_global_load_lds(
        (const __attribute__((address_space(1))) unsigned int*)vs0,
        (__attribute__((address_space(3))) unsigned int*)&Vs[buf][ci0 * 8], 16, 0, 0);
    __builtin_amdgcn_global_load_lds(
        (const __attribute__((address_space(1))) unsigned int*)vs1,
        (__attribute__((address_space(3))) unsigned int*)&Vs[buf][ci1 * 8], 16, 0, 0);
    ks0 += 4096; ks1 += 4096;  // +64 K-rows
    vs0 += 64; vs1 += 64;      // +64 kv-cols
  };

  auto qkt = [&](f32x16* sacc, const unsigned short* K_, int kv0) {
    sacc[0] = f32x16{};
    sacc[1] = f32x16{};
    __builtin_amdgcn_s_setprio(1);
#pragma unroll
    for (int kc = 0; kc < 4; ++kc) {
      bf16x8 kf0 = *reinterpret_cast<const bf16x8*>(
          &K_[l31 * 64 + ((2 * kc + hb) ^ x7) * 8]);
      bf16x8 kf1 = *reinterpret_cast<const bf16x8*>(
          &K_[(32 + l31) * 64 + ((2 * kc + hb) ^ x7) * 8]);
      sacc[0] = MFMA32(kf0, qg[kc], sacc[0]);
      sacc[1] = MFMA32(kf1, qg[kc], sacc[1]);
    }
    __builtin_amdgcn_s_setprio(0);
    if (kv0 + 63 > qw) {
      const int qrel = qw + l31 - kv0 - 8 * hb;
#pragma unroll
      for (int mi = 0; mi < 2; ++mi)
#pragma unroll
        for (int r = 0; r < 16; ++r) {
          int koff = (r & 7) + 16 * (r >> 3) + 32 * mi;
          if (koff > qrel) sacc[mi][r] = -1e30f;
        }
    }
  };

  auto finish = [&](const f32x16* sacc, const unsigned short* V_) {
    unsigned pw[2][8];
#pragma unroll
    for (int mi = 0; mi < 2; ++mi)
#pragma unroll
      for (int i = 0; i < 8; ++i) {
        float pa = __builtin_amdgcn_exp2f(sacc[mi][2 * i]);
        float pb = __builtin_amdgcn_exp2f(sacc[mi][2 * i + 1]);
        pw[mi][i] = cvtpk(pa, pb);
      }
    __builtin_amdgcn_s_setprio(1);
#pragma unroll
    for (int c = 0; c < 4; ++c) {
      union { unsigned u[4]; bf16x8 v; } pu;
      pu.u[0] = pw[c >> 1][(c & 1) * 4 + 0];
      pu.u[1] = pw[c >> 1][(c & 1) * 4 + 1];
      pu.u[2] = pw[c >> 1][(c & 1) * 4 + 2];
      pu.u[3] = pw[c >> 1][(c & 1) * 4 + 3];
#pragma unroll
      for (int db = 0; db < 2; ++db) {
        bf16x8 vf = *reinterpret_cast<const bf16x8*>(
            &V_[(32 * db + l31) * 64 + ((2 * c + hb) ^ x7) * 8]);
        o[db] = MFMA32(vf, pu.v, o[db]);
      }
      ls = MFMA32(ones, pu.v, ls);
    }
    __builtin_amdgcn_s_setprio(0);
  };

  stage(0);
  stage(1);

  f32x16 sA[2], sB[2];

  for (int it = 0; it < nt; it += 2) {
    if (it < nt - 1) asm volatile("s_waitcnt vmcnt(4)" ::: "memory");
    else             asm volatile("s_waitcnt vmcnt(0)" ::: "memory");
    __builtin_amdgcn_s_barrier();
    __builtin_amdgcn_sched_barrier(0);
    {
      const int kv0 = 64 * it;
      if (kv0 <= qw + 31) qkt(sA, Ks[it % 3], kv0);
      if (it > 0 && kv0 - 64 <= qw + 31) finish(sB, Vs[(it - 1) % 3]);
      if (it + 2 < nt) {
        __builtin_amdgcn_s_barrier();
        __builtin_amdgcn_sched_barrier(0);
        stage((it + 2) % 3);
      }
    }
    const int it1 = it + 1;
    if (it1 < nt - 1) asm volatile("s_waitcnt vmcnt(4)" ::: "memory");
    else              asm volatile("s_waitcnt vmcnt(0)" ::: "memory");
    __builtin_amdgcn_s_barrier();
    __builtin_amdgcn_sched_barrier(0);
    {
      const int kv0 = 64 * it1;
      if (kv0 <= qw + 31) qkt(sB, Ks[it1 % 3], kv0);
      if (kv0 - 64 <= qw + 31) finish(sA, Vs[it % 3]);
      if (it1 + 2 < nt) {
        __builtin_amdgcn_s_barrier();
        __builtin_amdgcn_sched_barrier(0);
        stage((it1 + 2) % 3);
      }
    }
  }
  if (64 * (nt - 1) <= qw + 31) finish(sB, Vs[(nt - 1) % 3]);

  const float inv = 1.0f / ls[0];
  const int b = bh >> 4, h = bh & 15;
  const int q = qw + l31;
  unsigned short* cp = ctx + ((size_t)(b * 2048 + q) * 1024) + h * 64;
#pragma unroll
  for (int db = 0; db < 2; ++db)
#pragma unroll
    for (int i = 0; i < 8; ++i) {
      unsigned w = cvtpk(o[db][2 * i] * inv, o[db][2 * i + 1] * inv);
      int d = 32 * db + ((2 * i) & 3) + 8 * (i >> 1) + 4 * hb;
      *reinterpret_cast<unsigned*>(cp + d) = w;
    }
}

extern "C" void kernel_launch(void* const* d_in, const int* in_sizes, int n_in,
                              void* d_out, int out_size, void* d_ws, size_t ws_size,
                              hipStream_t stream) {
  const float* in_q = (const float*)d_in[0];
  const float* in_k = (const float*)d_in[1];
  const float* in_v = (const float*)d_in[2];
  const float* WQw = (const float*)d_in[3];
  const float* WQb = (const float*)d_in[4];
  const float* WKw = (const float*)d_in[5];
  const float* WKb = (const float*)d_in[6];
  const float* WVw = (const float*)d_in[7];
  const float* WVb = (const float*)d_in[8];
  const float* Ww  = (const float*)d_in[9];
  const float* Wb  = (const float*)d_in[10];
  float* out = (float*)d_out;

  constexpr size_t PROJ = (size_t)4 * 16 * 2048 * 64;  // 8,388,608 elems
  constexpr size_t WSZ = (size_t)1024 * 1024;
  const float qscale = 0.03125f * 1.4426950408889634f;  // 1/sqrt(1024) * log2(e)
  unsigned short* wsp = (unsigned short*)d_ws;

  const bool fused = ws_size >= (6 * PROJ + 4 * WSZ) * sizeof(unsigned short);

  if (fused) {
    unsigned short* Qp   = wsp;
    unsigned short* Kp   = wsp + PROJ;
    unsigned short* Vt   = wsp + 2 * PROJ;
    unsigned short* inq  = wsp + 3 * PROJ;  // later aliased as ctx
    unsigned short* ctx  = inq;
    unsigned short* ink  = wsp + 4 * PROJ;
    unsigned short* inv  = wsp + 5 * PROJ;
    unsigned short* wq16 = wsp + 6 * PROJ;
    unsigned short* wk16 = wq16 + WSZ;
    unsigned short* wv16 = wk16 + WSZ;
    unsigned short* ww16 = wv16 + WSZ;

    cvt_first_kernel<<<dim3(1024, 5), 256, 0, stream>>>(
        WQw, WKw, WVw, Ww, wq16, wk16, wv16, ww16, (int)(WSZ / 8),
        in_q, inq, (int)(PROJ / 8));
    gemm_kernel<0><<<2560, 256, 0, stream>>>(inq, wq16, WQb, Qp, 8192, 1024, 1024,
                                             qscale, 3, 512, in_k, ink, (int)(PROJ / 8));
    gemm_kernel<0><<<2560, 256, 0, stream>>>(ink, wk16, WKb, Kp, 8192, 1024, 1024,
                                             1.0f, 3, 512, in_v, inv, (int)(PROJ / 8));
    gemm_kernel<2><<<512, 256, 0, stream>>>(wv16, inv, WVb, Vt, 1024, 8192, 1024,
                                            1.0f, 6, 512, nullptr, nullptr, 0);
    attn9_kernel<<<1024, 256, 0, stream>>>(Qp, Kp, Vt, ctx);
    gemm_kernel<1><<<512, 256, 0, stream>>>(ctx, ww16, Wb, out, 8192, 1024, 1024,
                                            1.0f, 3, 512, nullptr, nullptr, 0);
  } else {
    unsigned short* Qp   = wsp;
    unsigned short* Kp   = wsp + PROJ;
    unsigned short* Vt   = wsp + 2 * PROJ;
    unsigned short* in16 = wsp + 3 * PROJ;
    unsigned short* ctx  = in16;
    unsigned short* wq16 = wsp + 4 * PROJ;
    unsigned short* wk16 = wq16 + WSZ;
    unsigned short* wv16 = wk16 + WSZ;
    unsigned short* ww16 = wv16 + WSZ;

    cvt_first_kernel<<<dim3(1024, 5), 256, 0, stream>>>(
        WQw, WKw, WVw, Ww, wq16, wk16, wv16, ww16, (int)(WSZ / 8),
        in_q, in16, (int)(PROJ / 8));
    gemm_kernel<0><<<512, 256, 0, stream>>>(in16, wq16, WQb, Qp, 8192, 1024, 1024,
                                            qscale, 3, 512, nullptr, nullptr, 0);
    cvt1_kernel<<<2048, 256, 0, stream>>>(in_k, in16, (int)(PROJ / 8));
    gemm_kernel<0><<<512, 256, 0, stream>>>(in16, wk16, WKb, Kp, 8192, 1024, 1024,
                                            1.0f, 3, 512, nullptr, nullptr, 0);
    cvt1_kernel<<<2048, 256, 0, stream>>>(in_v, in16, (int)(PROJ / 8));
    gemm_kernel<2><<<512, 256, 0, stream>>>(wv16, in16, WVb, Vt, 1024, 8192, 1024,
                                            1.0f, 6, 512, nullptr, nullptr, 0);
    attn9_kernel<<<1024, 256, 0, stream>>>(Qp, Kp, Vt, ctx);
    gemm_kernel<1><<<512, 256, 0, stream>>>(ctx, ww16, Wb, out, 8192, 1024, 1024,
                                            1.0f, 3, 512, nullptr, nullptr, 0);
  }
}

// Round 21
// 169.547 us; speedup vs baseline: 1.0689x; 1.0048x over previous
//
#include <hip/hip_runtime.h>
#include <hip/hip_bf16.h>

typedef __attribute__((ext_vector_type(8))) short bf16x8;
typedef __attribute__((ext_vector_type(4))) float f32x4;
typedef __attribute__((ext_vector_type(16))) float f32x16;
typedef __attribute__((ext_vector_type(4))) unsigned uint4v;

#define MFMA16(a, b, c) __builtin_amdgcn_mfma_f32_16x16x32_bf16(a, b, c, 0, 0, 0)
#define MFMA32(a, b, c) __builtin_amdgcn_mfma_f32_32x32x16_bf16(a, b, c, 0, 0, 0)

__device__ __forceinline__ unsigned short f2bfn(float f) {
#if defined(__gfx950__)
  __bf16 h = (__bf16)f;
  return __builtin_bit_cast(unsigned short, h);
#else
  union { float f; unsigned u; } x; x.f = f;
  unsigned r = x.u + 0x7fffu + ((x.u >> 16) & 1u);
  return (unsigned short)(r >> 16);
#endif
}

__device__ __forceinline__ unsigned cvtpk(float lo, float hi) {
  unsigned w;
  asm("v_cvt_pk_bf16_f32 %0, %1, %2" : "=v"(w) : "v"(lo), "v"(hi));
  return w;
}

// ---------------- fp32 -> bf16 conversion ----------------
__device__ __forceinline__ void cvt_range(const float* __restrict__ s,
                                          unsigned short* __restrict__ d,
                                          int i, int st, int n8) {
  for (; i < n8; i += st) {
    const float4* sp = reinterpret_cast<const float4*>(s) + 2 * (size_t)i;
    float4 a = sp[0], b = sp[1];
    uint4v o;
    o[0] = cvtpk(a.x, a.y); o[1] = cvtpk(a.z, a.w);
    o[2] = cvtpk(b.x, b.y); o[3] = cvtpk(b.z, b.w);
    reinterpret_cast<uint4v*>(d)[i] = o;
  }
}

__global__ void cvt1_kernel(const float* __restrict__ s, unsigned short* __restrict__ d, int n8) {
  cvt_range(s, d, blockIdx.x * blockDim.x + threadIdx.x, gridDim.x * blockDim.x, n8);
}

// y<4: weight matrices; y==4: Q input (larger, grid-strided)
__global__ void cvt_first_kernel(const float* s0, const float* s1, const float* s2,
                                 const float* s3, unsigned short* d0, unsigned short* d1,
                                 unsigned short* d2, unsigned short* d3, int wn8,
                                 const float* sq, unsigned short* dq, int qn8) {
  const float* s; unsigned short* d; int n8;
  switch (blockIdx.y) {
    case 0: s = s0; d = d0; n8 = wn8; break;
    case 1: s = s1; d = d1; n8 = wn8; break;
    case 2: s = s2; d = d2; n8 = wn8; break;
    case 3: s = s3; d = d3; n8 = wn8; break;
    default: s = sq; d = dq; n8 = qn8; break;
  }
  cvt_range(s, d, blockIdx.x * blockDim.x + threadIdx.x, gridDim.x * blockDim.x, n8);
}

// ---------------- GEMM (proven BK=64 config) ----------------
// 1D grid: n = sx & (2^nshift-1), m = sx >> nshift; nshift==3 gets the
// XCD-chunk swizzle (4MB working set per XCD). Blocks bx >= ngemm piggyback cvt.
// MODE 0: bias[col], out bf16 scattered [B,H,S,64], *oscale
// MODE 1: bias[col], out fp32 row-major [M,N]
// MODE 2: bias[row], out bf16 V^T [BH,64,S]
template <int MODE>
__global__ __launch_bounds__(256) void gemm_kernel(
    const unsigned short* __restrict__ Av, const unsigned short* __restrict__ Bv,
    const float* __restrict__ bias, void* __restrict__ outv,
    int M, int N, int K, float oscale, int nshift, int ngemm,
    const float* __restrict__ csrc, unsigned short* __restrict__ cdst, int cn8) {
  constexpr int BM = 128, BN = 128, BK = 64;
  __shared__ __align__(16) unsigned short As[2][BM * BK];
  __shared__ __align__(16) unsigned short Bs[2][BN * BK];
  const int bx = blockIdx.x;
  const int tid = threadIdx.x;
  if (bx >= ngemm) {
    cvt_range(csrc, cdst, (bx - ngemm) * blockDim.x + tid,
              (gridDim.x - ngemm) * blockDim.x, cn8);
    return;
  }
  int sx = bx;
  if (nshift == 3) sx = (bx & 7) * (ngemm >> 3) + (bx >> 3);
  const int lane = tid & 63, wave = tid >> 6;
  const int wr = wave >> 1, wc = wave & 1;
  const int m0 = (sx >> nshift) * BM, n0 = (sx & ((1 << nshift) - 1)) * BN;
  const int rb = lane & 15, g = lane >> 4;
  const int swz = ((lane & 7) ^ ((lane >> 3) & 7)) * 8;
  f32x4 acc[4][4] = {};

  const unsigned short* Ab = Av + (size_t)m0 * K;
  const unsigned short* Bb = Bv + (size_t)n0 * K;

  auto stage = [&](int buf, int k0) {
#pragma unroll
    for (int i = 0; i < 4; ++i) {
      const int c = wave * 256 + i * 64 + lane;
      const int r = c >> 3;
      __builtin_amdgcn_global_load_lds(
          (const __attribute__((address_space(1))) unsigned int*)(Ab + (size_t)r * K + k0 + swz),
          (__attribute__((address_space(3))) unsigned int*)&As[buf][c * 8], 16, 0, 0);
      __builtin_amdgcn_global_load_lds(
          (const __attribute__((address_space(1))) unsigned int*)(Bb + (size_t)r * K + k0 + swz),
          (__attribute__((address_space(3))) unsigned int*)&Bs[buf][c * 8], 16, 0, 0);
    }
  };

  const int nt = K / BK;
  stage(0, 0);
  int cur = 0;
  for (int t = 0; t < nt; ++t) {
    __syncthreads();
    if (t + 1 < nt) stage(cur ^ 1, (t + 1) * BK);
    const unsigned short* A_ = As[cur];
    const unsigned short* B_ = Bs[cur];
#pragma unroll
    for (int kc = 0; kc < 2; ++kc) {
      bf16x8 af[4], bfr[4];
#pragma unroll
      for (int mi = 0; mi < 4; ++mi)
        af[mi] = *reinterpret_cast<const bf16x8*>(
            &A_[(wr * 64 + mi * 16 + rb) * 64 + (((kc * 4 + g) ^ (rb & 7)) * 8)]);
#pragma unroll
      for (int ni = 0; ni < 4; ++ni)
        bfr[ni] = *reinterpret_cast<const bf16x8*>(
            &B_[(wc * 64 + ni * 16 + rb) * 64 + (((kc * 4 + g) ^ (rb & 7)) * 8)]);
#pragma unroll
      for (int mi = 0; mi < 4; ++mi)
#pragma unroll
        for (int ni = 0; ni < 4; ++ni)
          acc[mi][ni] = MFMA16(af[mi], bfr[ni], acc[mi][ni]);
    }
    cur ^= 1;
  }

#pragma unroll
  for (int mi = 0; mi < 4; ++mi) {
#pragma unroll
    for (int ni = 0; ni < 4; ++ni) {
      int col = n0 + wc * 64 + ni * 16 + rb;
      if constexpr (MODE != 2) {
        float bvv = bias[col];
#pragma unroll
        for (int j = 0; j < 4; ++j) {
          int row = m0 + wr * 64 + mi * 16 + g * 4 + j;
          float v = acc[mi][ni][j] + bvv;
          if constexpr (MODE == 0) {
            v *= oscale;
            int b = row >> 11, s = row & 2047;
            int h = col >> 6, e = col & 63;
            ((unsigned short*)outv)[((size_t)(b * 16 + h) * 2048 + s) * 64 + e] = f2bfn(v);
          } else {
            ((float*)outv)[(size_t)row * N + col] = v;
          }
        }
      } else {
        int bb = col >> 11, s = col & 2047;
#pragma unroll
        for (int j = 0; j < 4; ++j) {
          int row = m0 + wr * 64 + mi * 16 + g * 4 + j;
          float v = acc[mi][ni][j] + bias[row];
          int h = row >> 6, e = row & 63;
          ((unsigned short*)outv)[((size_t)(bb * 16 + h) * 64 + e) * 2048 + s] = f2bfn(v);
        }
      }
    }
  }
}

// ---------------- flash attention: T15 double-pipeline, 4 buffers, 1 barrier/sub-iter ----------------
// vs r18: a 4th LDS buffer removes the second barrier — stage(it+2) targets
// (it+2)&3, whose last readers (qkt at it-2; finish(it-2) inside region it-1)
// are separated from this region by the sub-iter's single barrier. vmcnt logic
// unchanged (outstanding stages at the wait = {it, it+1} = 8 loads; vmcnt(4)
// retires exactly tile it, FIFO). LDS 64KB -> 2 blocks/CU (measured effective
// occupancy ~5.8 waves/CU < the 8-wave cap, so the cap shouldn't bind).
__global__ __launch_bounds__(256) void attn10_kernel(
    const unsigned short* __restrict__ Qp, const unsigned short* __restrict__ Kp,
    const unsigned short* __restrict__ Vtp, unsigned short* __restrict__ ctx) {
  constexpr int S = 2048;
  __shared__ __align__(16) unsigned short Ks[4][64 * 64];
  __shared__ __align__(16) unsigned short Vs[4][64 * 64];
  const int bx = blockIdx.x;
  const int bh = bx & 63;
  const int qti = 15 - (bx >> 6);  // heavy tiles first
  const int tid = threadIdx.x, wave = tid >> 6, lane = tid & 63;
  const int l31 = lane & 31, hb = lane >> 5;
  const int x7 = l31 & 7;
  const int qw = qti * 128 + wave * 32;
  const unsigned short* Qb = Qp + (size_t)bh * S * 64;
  const unsigned short* Kb = Kp + (size_t)bh * S * 64;
  const unsigned short* Vb = Vtp + (size_t)bh * 64 * S;

  bf16x8 qg[4];
#pragma unroll
  for (int kc = 0; kc < 4; ++kc)
    qg[kc] = *reinterpret_cast<const bf16x8*>(
        Qb + (size_t)(qw + l31) * 64 + 16 * kc + 8 * hb);

  bf16x8 ones;
#pragma unroll
  for (int i = 0; i < 8; ++i) ones[i] = (short)0x3F80;

  f32x16 ls = {};
  f32x16 o[2] = {};
  const int sswz = ((lane & 7) ^ (lane >> 3)) * 8;
  const int nt = qti * 2 + 2;  // always even

  const int ci0 = wave * 2 * 64 + lane, ci1 = ci0 + 64;
  const int r0 = wave * 16 + (lane >> 3), r1 = r0 + 8;
  const int rs0 = (r0 & 51) | ((r0 & 4) << 1) | ((r0 & 8) >> 1);
  const int rs1 = (r1 & 51) | ((r1 & 4) << 1) | ((r1 & 8) >> 1);
  const unsigned short* ks0 = Kb + (size_t)rs0 * 64 + sswz;
  const unsigned short* ks1 = Kb + (size_t)rs1 * 64 + sswz;
  const unsigned short* vs0 = Vb + (size_t)r0 * S + sswz;
  const unsigned short* vs1 = Vb + (size_t)r1 * S + sswz;

  auto stage = [&](int buf) {
    __builtin_amdgcn_global_load_lds(
        (const __attribute__((address_space(1))) unsigned int*)ks0,
        (__attribute__((address_space(3))) unsigned int*)&Ks[buf][ci0 * 8], 16, 0, 0);
    __builtin_amdgcn_global_load_lds(
        (const __attribute__((address_space(1))) unsigned int*)ks1,
        (__attribute__((address_space(3))) unsigned int*)&Ks[buf][ci1 * 8], 16, 0, 0);
    __builtin_amdgcn_global_load_lds(
        (const __attribute__((address_space(1))) unsigned int*)vs0,
        (__attribute__((address_space(3))) unsigned int*)&Vs[buf][ci0 * 8], 16, 0, 0);
    __builtin_amdgcn_global_load_lds(
        (const __attribute__((address_space(1))) unsigned int*)vs1,
        (__attribute__((address_space(3))) unsigned int*)&Vs[buf][ci1 * 8], 16, 0, 0);
    ks0 += 4096; ks1 += 4096;  // +64 K-rows
    vs0 += 64; vs1 += 64;      // +64 kv-cols
  };

  auto qkt = [&](f32x16* sacc, const unsigned short* K_, int kv0) {
    sacc[0] = f32x16{};
    sacc[1] = f32x16{};
    __builtin_amdgcn_s_setprio(1);
#pragma unroll
    for (int kc = 0; kc < 4; ++kc) {
      bf16x8 kf0 = *reinterpret_cast<const bf16x8*>(
          &K_[l31 * 64 + ((2 * kc + hb) ^ x7) * 8]);
      bf16x8 kf1 = *reinterpret_cast<const bf16x8*>(
          &K_[(32 + l31) * 64 + ((2 * kc + hb) ^ x7) * 8]);
      sacc[0] = MFMA32(kf0, qg[kc], sacc[0]);
      sacc[1] = MFMA32(kf1, qg[kc], sacc[1]);
    }
    __builtin_amdgcn_s_setprio(0);
    if (kv0 + 63 > qw) {
      const int qrel = qw + l31 - kv0 - 8 * hb;
#pragma unroll
      for (int mi = 0; mi < 2; ++mi)
#pragma unroll
        for (int r = 0; r < 16; ++r) {
          int koff = (r & 7) + 16 * (r >> 3) + 32 * mi;
          if (koff > qrel) sacc[mi][r] = -1e30f;
        }
    }
  };

  auto finish = [&](const f32x16* sacc, const unsigned short* V_) {
    unsigned pw[2][8];
#pragma unroll
    for (int mi = 0; mi < 2; ++mi)
#pragma unroll
      for (int i = 0; i < 8; ++i) {
        float pa = __builtin_amdgcn_exp2f(sacc[mi][2 * i]);
        float pb = __builtin_amdgcn_exp2f(sacc[mi][2 * i + 1]);
        pw[mi][i] = cvtpk(pa, pb);
      }
    __builtin_amdgcn_s_setprio(1);
#pragma unroll
    for (int c = 0; c < 4; ++c) {
      union { unsigned u[4]; bf16x8 v; } pu;
      pu.u[0] = pw[c >> 1][(c & 1) * 4 + 0];
      pu.u[1] = pw[c >> 1][(c & 1) * 4 + 1];
      pu.u[2] = pw[c >> 1][(c & 1) * 4 + 2];
      pu.u[3] = pw[c >> 1][(c & 1) * 4 + 3];
#pragma unroll
      for (int db = 0; db < 2; ++db) {
        bf16x8 vf = *reinterpret_cast<const bf16x8*>(
            &V_[(32 * db + l31) * 64 + ((2 * c + hb) ^ x7) * 8]);
        o[db] = MFMA32(vf, pu.v, o[db]);
      }
      ls = MFMA32(ones, pu.v, ls);
    }
    __builtin_amdgcn_s_setprio(0);
  };

  stage(0);
  stage(1);

  f32x16 sA[2], sB[2];

  for (int it = 0; it < nt; it += 2) {
    // ---- even sub-iter: QKT(it) -> sA ; finish(it-1) from sB ; stage(it+2) ----
    if (it < nt - 1) asm volatile("s_waitcnt vmcnt(4)" ::: "memory");
    else             asm volatile("s_waitcnt vmcnt(0)" ::: "memory");
    __builtin_amdgcn_s_barrier();
    __builtin_amdgcn_sched_barrier(0);
    {
      const int kv0 = 64 * it;
      if (kv0 <= qw + 31) qkt(sA, Ks[it & 3], kv0);
      if (it > 0 && kv0 - 64 <= qw + 31) finish(sB, Vs[(it - 1) & 3]);
      if (it + 2 < nt) stage((it + 2) & 3);
    }
    // ---- odd sub-iter: QKT(it+1) -> sB ; finish(it) from sA ; stage(it+3) ----
    const int it1 = it + 1;
    if (it1 < nt - 1) asm volatile("s_waitcnt vmcnt(4)" ::: "memory");
    else              asm volatile("s_waitcnt vmcnt(0)" ::: "memory");
    __builtin_amdgcn_s_barrier();
    __builtin_amdgcn_sched_barrier(0);
    {
      const int kv0 = 64 * it1;
      if (kv0 <= qw + 31) qkt(sB, Ks[it1 & 3], kv0);
      if (kv0 - 64 <= qw + 31) finish(sA, Vs[it & 3]);
      if (it1 + 2 < nt) stage((it1 + 2) & 3);
    }
  }
  // drain: finish last tile (nt-1, held in sB)
  if (64 * (nt - 1) <= qw + 31) finish(sB, Vs[(nt - 1) & 3]);

  // ---- epilogue: lane holds O^T[d = 32db+(r&3)+8(r>>2)+4hb][q = qw+l31] ----
  const float inv = 1.0f / ls[0];
  const int b = bh >> 4, h = bh & 15;
  const int q = qw + l31;
  unsigned short* cp = ctx + ((size_t)(b * 2048 + q) * 1024) + h * 64;
#pragma unroll
  for (int db = 0; db < 2; ++db)
#pragma unroll
    for (int i = 0; i < 8; ++i) {
      unsigned w = cvtpk(o[db][2 * i] * inv, o[db][2 * i + 1] * inv);
      int d = 32 * db + ((2 * i) & 3) + 8 * (i >> 1) + 4 * hb;
      *reinterpret_cast<unsigned*>(cp + d) = w;
    }
}

extern "C" void kernel_launch(void* const* d_in, const int* in_sizes, int n_in,
                              void* d_out, int out_size, void* d_ws, size_t ws_size,
                              hipStream_t stream) {
  const float* in_q = (const float*)d_in[0];
  const float* in_k = (const float*)d_in[1];
  const float* in_v = (const float*)d_in[2];
  const float* WQw = (const float*)d_in[3];
  const float* WQb = (const float*)d_in[4];
  const float* WKw = (const float*)d_in[5];
  const float* WKb = (const float*)d_in[6];
  const float* WVw = (const float*)d_in[7];
  const float* WVb = (const float*)d_in[8];
  const float* Ww  = (const float*)d_in[9];
  const float* Wb  = (const float*)d_in[10];
  float* out = (float*)d_out;

  constexpr size_t PROJ = (size_t)4 * 16 * 2048 * 64;  // 8,388,608 elems
  constexpr size_t WSZ = (size_t)1024 * 1024;
  const float qscale = 0.03125f * 1.4426950408889634f;  // 1/sqrt(1024) * log2(e)
  unsigned short* wsp = (unsigned short*)d_ws;

  const bool fused = ws_size >= (6 * PROJ + 4 * WSZ) * sizeof(unsigned short);

  if (fused) {
    unsigned short* Qp   = wsp;
    unsigned short* Kp   = wsp + PROJ;
    unsigned short* Vt   = wsp + 2 * PROJ;
    unsigned short* inq  = wsp + 3 * PROJ;  // later aliased as ctx
    unsigned short* ctx  = inq;
    unsigned short* ink  = wsp + 4 * PROJ;
    unsigned short* inv  = wsp + 5 * PROJ;
    unsigned short* wq16 = wsp + 6 * PROJ;
    unsigned short* wk16 = wq16 + WSZ;
    unsigned short* wv16 = wk16 + WSZ;
    unsigned short* ww16 = wv16 + WSZ;

    cvt_first_kernel<<<dim3(1024, 5), 256, 0, stream>>>(
        WQw, WKw, WVw, Ww, wq16, wk16, wv16, ww16, (int)(WSZ / 8),
        in_q, inq, (int)(PROJ / 8));
    gemm_kernel<0><<<2560, 256, 0, stream>>>(inq, wq16, WQb, Qp, 8192, 1024, 1024,
                                             qscale, 3, 512, in_k, ink, (int)(PROJ / 8));
    gemm_kernel<0><<<2560, 256, 0, stream>>>(ink, wk16, WKb, Kp, 8192, 1024, 1024,
                                             1.0f, 3, 512, in_v, inv, (int)(PROJ / 8));
    gemm_kernel<2><<<512, 256, 0, stream>>>(wv16, inv, WVb, Vt, 1024, 8192, 1024,
                                            1.0f, 6, 512, nullptr, nullptr, 0);
    attn10_kernel<<<1024, 256, 0, stream>>>(Qp, Kp, Vt, ctx);
    gemm_kernel<1><<<512, 256, 0, stream>>>(ctx, ww16, Wb, out, 8192, 1024, 1024,
                                            1.0f, 3, 512, nullptr, nullptr, 0);
  } else {
    unsigned short* Qp   = wsp;
    unsigned short* Kp   = wsp + PROJ;
    unsigned short* Vt   = wsp + 2 * PROJ;
    unsigned short* in16 = wsp + 3 * PROJ;
    unsigned short* ctx  = in16;
    unsigned short* wq16 = wsp + 4 * PROJ;
    unsigned short* wk16 = wq16 + WSZ;
    unsigned short* wv16 = wk16 + WSZ;
    unsigned short* ww16 = wv16 + WSZ;

    cvt_first_kernel<<<dim3(1024, 5), 256, 0, stream>>>(
        WQw, WKw, WVw, Ww, wq16, wk16, wv16, ww16, (int)(WSZ / 8),
        in_q, in16, (int)(PROJ / 8));
    gemm_kernel<0><<<512, 256, 0, stream>>>(in16, wq16, WQb, Qp, 8192, 1024, 1024,
                                            qscale, 3, 512, nullptr, nullptr, 0);
    cvt1_kernel<<<2048, 256, 0, stream>>>(in_k, in16, (int)(PROJ / 8));
    gemm_kernel<0><<<512, 256, 0, stream>>>(in16, wk16, WKb, Kp, 8192, 1024, 1024,
                                            1.0f, 3, 512, nullptr, nullptr, 0);
    cvt1_kernel<<<2048, 256, 0, stream>>>(in_v, in16, (int)(PROJ / 8));
    gemm_kernel<2><<<512, 256, 0, stream>>>(wv16, in16, WVb, Vt, 1024, 8192, 1024,
                                            1.0f, 6, 512, nullptr, nullptr, 0);
    attn10_kernel<<<1024, 256, 0, stream>>>(Qp, Kp, Vt, ctx);
    gemm_kernel<1><<<512, 256, 0, stream>>>(ctx, ww16, Wb, out, 8192, 1024, 1024,
                                            1.0f, 3, 512, nullptr, nullptr, 0);
  }
}

// Round 23
// 167.847 us; speedup vs baseline: 1.0797x; 1.0101x over previous
//
#include <hip/hip_runtime.h>
#include <hip/hip_bf16.h>

typedef __attribute__((ext_vector_type(8))) short bf16x8;
typedef __attribute__((ext_vector_type(4))) float f32x4;
typedef __attribute__((ext_vector_type(16))) float f32x16;
typedef __attribute__((ext_vector_type(4))) unsigned uint4v;

#define MFMA16(a, b, c) __builtin_amdgcn_mfma_f32_16x16x32_bf16(a, b, c, 0, 0, 0)
#define MFMA32(a, b, c) __builtin_amdgcn_mfma_f32_32x32x16_bf16(a, b, c, 0, 0, 0)

__device__ __forceinline__ unsigned short f2bfn(float f) {
#if defined(__gfx950__)
  __bf16 h = (__bf16)f;
  return __builtin_bit_cast(unsigned short, h);
#else
  union { float f; unsigned u; } x; x.f = f;
  unsigned r = x.u + 0x7fffu + ((x.u >> 16) & 1u);
  return (unsigned short)(r >> 16);
#endif
}

__device__ __forceinline__ unsigned cvtpk(float lo, float hi) {
  unsigned w;
  asm("v_cvt_pk_bf16_f32 %0, %1, %2" : "=v"(w) : "v"(lo), "v"(hi));
  return w;
}

// ---------------- fp32 -> bf16 conversion ----------------
__device__ __forceinline__ void cvt_range(const float* __restrict__ s,
                                          unsigned short* __restrict__ d,
                                          int i, int st, int n8) {
  for (; i < n8; i += st) {
    const float4* sp = reinterpret_cast<const float4*>(s) + 2 * (size_t)i;
    float4 a = sp[0], b = sp[1];
    uint4v o;
    o[0] = cvtpk(a.x, a.y); o[1] = cvtpk(a.z, a.w);
    o[2] = cvtpk(b.x, b.y); o[3] = cvtpk(b.z, b.w);
    reinterpret_cast<uint4v*>(d)[i] = o;
  }
}

__global__ void cvt1_kernel(const float* __restrict__ s, unsigned short* __restrict__ d, int n8) {
  cvt_range(s, d, blockIdx.x * blockDim.x + threadIdx.x, gridDim.x * blockDim.x, n8);
}

// y<4: weight matrices; y==4: Q input (larger, grid-strided)
__global__ void cvt_first_kernel(const float* s0, const float* s1, const float* s2,
                                 const float* s3, unsigned short* d0, unsigned short* d1,
                                 unsigned short* d2, unsigned short* d3, int wn8,
                                 const float* sq, unsigned short* dq, int qn8) {
  const float* s; unsigned short* d; int n8;
  switch (blockIdx.y) {
    case 0: s = s0; d = d0; n8 = wn8; break;
    case 1: s = s1; d = d1; n8 = wn8; break;
    case 2: s = s2; d = d2; n8 = wn8; break;
    case 3: s = s3; d = d3; n8 = wn8; break;
    default: s = sq; d = dq; n8 = qn8; break;
  }
  cvt_range(s, d, blockIdx.x * blockDim.x + threadIdx.x, gridDim.x * blockDim.x, n8);
}

// ---------------- GEMM (proven BK=64 config) ----------------
// 1D grid: n = sx & (2^nshift-1), m = sx >> nshift; nshift==3 gets the
// XCD-chunk swizzle (4MB working set per XCD). Blocks bx >= ngemm piggyback cvt.
// MODE 0: bias[col], out bf16 scattered [B,H,S,64], *oscale
// MODE 1: bias[col], out fp32 row-major [M,N]
// MODE 2: bias[row], out bf16 V^T [BH,64,S]
template <int MODE>
__global__ __launch_bounds__(256) void gemm_kernel(
    const unsigned short* __restrict__ Av, const unsigned short* __restrict__ Bv,
    const float* __restrict__ bias, void* __restrict__ outv,
    int M, int N, int K, float oscale, int nshift, int ngemm,
    const float* __restrict__ csrc, unsigned short* __restrict__ cdst, int cn8) {
  constexpr int BM = 128, BN = 128, BK = 64;
  __shared__ __align__(16) unsigned short As[2][BM * BK];
  __shared__ __align__(16) unsigned short Bs[2][BN * BK];
  const int bx = blockIdx.x;
  const int tid = threadIdx.x;
  if (bx >= ngemm) {
    cvt_range(csrc, cdst, (bx - ngemm) * blockDim.x + tid,
              (gridDim.x - ngemm) * blockDim.x, cn8);
    return;
  }
  int sx = bx;
  if (nshift == 3) sx = (bx & 7) * (ngemm >> 3) + (bx >> 3);
  const int lane = tid & 63, wave = tid >> 6;
  const int wr = wave >> 1, wc = wave & 1;
  const int m0 = (sx >> nshift) * BM, n0 = (sx & ((1 << nshift) - 1)) * BN;
  const int rb = lane & 15, g = lane >> 4;
  const int swz = ((lane & 7) ^ ((lane >> 3) & 7)) * 8;
  f32x4 acc[4][4] = {};

  const unsigned short* Ab = Av + (size_t)m0 * K;
  const unsigned short* Bb = Bv + (size_t)n0 * K;

  auto stage = [&](int buf, int k0) {
#pragma unroll
    for (int i = 0; i < 4; ++i) {
      const int c = wave * 256 + i * 64 + lane;
      const int r = c >> 3;
      __builtin_amdgcn_global_load_lds(
          (const __attribute__((address_space(1))) unsigned int*)(Ab + (size_t)r * K + k0 + swz),
          (__attribute__((address_space(3))) unsigned int*)&As[buf][c * 8], 16, 0, 0);
      __builtin_amdgcn_global_load_lds(
          (const __attribute__((address_space(1))) unsigned int*)(Bb + (size_t)r * K + k0 + swz),
          (__attribute__((address_space(3))) unsigned int*)&Bs[buf][c * 8], 16, 0, 0);
    }
  };

  const int nt = K / BK;
  stage(0, 0);
  int cur = 0;
  for (int t = 0; t < nt; ++t) {
    __syncthreads();
    if (t + 1 < nt) stage(cur ^ 1, (t + 1) * BK);
    const unsigned short* A_ = As[cur];
    const unsigned short* B_ = Bs[cur];
#pragma unroll
    for (int kc = 0; kc < 2; ++kc) {
      bf16x8 af[4], bfr[4];
#pragma unroll
      for (int mi = 0; mi < 4; ++mi)
        af[mi] = *reinterpret_cast<const bf16x8*>(
            &A_[(wr * 64 + mi * 16 + rb) * 64 + (((kc * 4 + g) ^ (rb & 7)) * 8)]);
#pragma unroll
      for (int ni = 0; ni < 4; ++ni)
        bfr[ni] = *reinterpret_cast<const bf16x8*>(
            &B_[(wc * 64 + ni * 16 + rb) * 64 + (((kc * 4 + g) ^ (rb & 7)) * 8)]);
#pragma unroll
      for (int mi = 0; mi < 4; ++mi)
#pragma unroll
        for (int ni = 0; ni < 4; ++ni)
          acc[mi][ni] = MFMA16(af[mi], bfr[ni], acc[mi][ni]);
    }
    cur ^= 1;
  }

#pragma unroll
  for (int mi = 0; mi < 4; ++mi) {
#pragma unroll
    for (int ni = 0; ni < 4; ++ni) {
      int col = n0 + wc * 64 + ni * 16 + rb;
      if constexpr (MODE != 2) {
        float bvv = bias[col];
#pragma unroll
        for (int j = 0; j < 4; ++j) {
          int row = m0 + wr * 64 + mi * 16 + g * 4 + j;
          float v = acc[mi][ni][j] + bvv;
          if constexpr (MODE == 0) {
            v *= oscale;
            int b = row >> 11, s = row & 2047;
            int h = col >> 6, e = col & 63;
            ((unsigned short*)outv)[((size_t)(b * 16 + h) * 2048 + s) * 64 + e] = f2bfn(v);
          } else {
            ((float*)outv)[(size_t)row * N + col] = v;
          }
        }
      } else {
        int bb = col >> 11, s = col & 2047;
#pragma unroll
        for (int j = 0; j < 4; ++j) {
          int row = m0 + wr * 64 + mi * 16 + g * 4 + j;
          float v = acc[mi][ni][j] + bias[row];
          int h = row >> 6, e = row & 63;
          ((unsigned short*)outv)[((size_t)(bb * 16 + h) * 64 + e) * 2048 + s] = f2bfn(v);
        }
      }
    }
  }
}

// ---------------- flash attention: T15 double-pipeline, 4 buffers, 1 barrier/sub-iter ----------------
// (round-21 proven: 58.0 us). stage(it+2) targets (it+2)&3, whose last readers
// (qkt at it-2; finish(it-2) inside region it-1) are separated from this region
// by the sub-iter's single barrier. vmcnt(4) retires exactly tile it (FIFO).
__global__ __launch_bounds__(256) void attn10_kernel(
    const unsigned short* __restrict__ Qp, const unsigned short* __restrict__ Kp,
    const unsigned short* __restrict__ Vtp, unsigned short* __restrict__ ctx) {
  constexpr int S = 2048;
  __shared__ __align__(16) unsigned short Ks[4][64 * 64];
  __shared__ __align__(16) unsigned short Vs[4][64 * 64];
  const int bx = blockIdx.x;
  const int bh = bx & 63;
  const int qti = 15 - (bx >> 6);  // heavy tiles first
  const int tid = threadIdx.x, wave = tid >> 6, lane = tid & 63;
  const int l31 = lane & 31, hb = lane >> 5;
  const int x7 = l31 & 7;
  const int qw = qti * 128 + wave * 32;
  const unsigned short* Qb = Qp + (size_t)bh * S * 64;
  const unsigned short* Kb = Kp + (size_t)bh * S * 64;
  const unsigned short* Vb = Vtp + (size_t)bh * 64 * S;

  bf16x8 qg[4];
#pragma unroll
  for (int kc = 0; kc < 4; ++kc)
    qg[kc] = *reinterpret_cast<const bf16x8*>(
        Qb + (size_t)(qw + l31) * 64 + 16 * kc + 8 * hb);

  bf16x8 ones;
#pragma unroll
  for (int i = 0; i < 8; ++i) ones[i] = (short)0x3F80;

  f32x16 ls = {};
  f32x16 o[2] = {};
  const int sswz = ((lane & 7) ^ (lane >> 3)) * 8;
  const int nt = qti * 2 + 2;  // always even

  const int ci0 = wave * 2 * 64 + lane, ci1 = ci0 + 64;
  const int r0 = wave * 16 + (lane >> 3), r1 = r0 + 8;
  const int rs0 = (r0 & 51) | ((r0 & 4) << 1) | ((r0 & 8) >> 1);
  const int rs1 = (r1 & 51) | ((r1 & 4) << 1) | ((r1 & 8) >> 1);
  const unsigned short* ks0 = Kb + (size_t)rs0 * 64 + sswz;
  const unsigned short* ks1 = Kb + (size_t)rs1 * 64 + sswz;
  const unsigned short* vs0 = Vb + (size_t)r0 * S + sswz;
  const unsigned short* vs1 = Vb + (size_t)r1 * S + sswz;

  auto stage = [&](int buf) {
    __builtin_amdgcn_global_load_lds(
        (const __attribute__((address_space(1))) unsigned int*)ks0,
        (__attribute__((address_space(3))) unsigned int*)&Ks[buf][ci0 * 8], 16, 0, 0);
    __builtin_amdgcn_global_load_lds(
        (const __attribute__((address_space(1))) unsigned int*)ks1,
        (__attribute__((address_space(3))) unsigned int*)&Ks[buf][ci1 * 8], 16, 0, 0);
    __builtin_amdgcn_global_load_lds(
        (const __attribute__((address_space(1))) unsigned int*)vs0,
        (__attribute__((address_space(3))) unsigned int*)&Vs[buf][ci0 * 8], 16, 0, 0);
    __builtin_amdgcn_global_load_lds(
        (const __attribute__((address_space(1))) unsigned int*)vs1,
        (__attribute__((address_space(3))) unsigned int*)&Vs[buf][ci1 * 8], 16, 0, 0);
    ks0 += 4096; ks1 += 4096;  // +64 K-rows
    vs0 += 64; vs1 += 64;      // +64 kv-cols
  };

  auto qkt = [&](f32x16* sacc, const unsigned short* K_, int kv0) {
    sacc[0] = f32x16{};
    sacc[1] = f32x16{};
    __builtin_amdgcn_s_setprio(1);
#pragma unroll
    for (int kc = 0; kc < 4; ++kc) {
      bf16x8 kf0 = *reinterpret_cast<const bf16x8*>(
          &K_[l31 * 64 + ((2 * kc + hb) ^ x7) * 8]);
      bf16x8 kf1 = *reinterpret_cast<const bf16x8*>(
          &K_[(32 + l31) * 64 + ((2 * kc + hb) ^ x7) * 8]);
      sacc[0] = MFMA32(kf0, qg[kc], sacc[0]);
      sacc[1] = MFMA32(kf1, qg[kc], sacc[1]);
    }
    __builtin_amdgcn_s_setprio(0);
    if (kv0 + 63 > qw) {
      const int qrel = qw + l31 - kv0 - 8 * hb;
#pragma unroll
      for (int mi = 0; mi < 2; ++mi)
#pragma unroll
        for (int r = 0; r < 16; ++r) {
          int koff = (r & 7) + 16 * (r >> 3) + 32 * mi;
          if (koff > qrel) sacc[mi][r] = -1e30f;
        }
    }
  };

  auto finish = [&](const f32x16* sacc, const unsigned short* V_) {
    unsigned pw[2][8];
#pragma unroll
    for (int mi = 0; mi < 2; ++mi)
#pragma unroll
      for (int i = 0; i < 8; ++i) {
        float pa = __builtin_amdgcn_exp2f(sacc[mi][2 * i]);
        float pb = __builtin_amdgcn_exp2f(sacc[mi][2 * i + 1]);
        pw[mi][i] = cvtpk(pa, pb);
      }
    __builtin_amdgcn_s_setprio(1);
#pragma unroll
    for (int c = 0; c < 4; ++c) {
      union { unsigned u[4]; bf16x8 v; } pu;
      pu.u[0] = pw[c >> 1][(c & 1) * 4 + 0];
      pu.u[1] = pw[c >> 1][(c & 1) * 4 + 1];
      pu.u[2] = pw[c >> 1][(c & 1) * 4 + 2];
      pu.u[3] = pw[c >> 1][(c & 1) * 4 + 3];
#pragma unroll
      for (int db = 0; db < 2; ++db) {
        bf16x8 vf = *reinterpret_cast<const bf16x8*>(
            &V_[(32 * db + l31) * 64 + ((2 * c + hb) ^ x7) * 8]);
        o[db] = MFMA32(vf, pu.v, o[db]);
      }
      ls = MFMA32(ones, pu.v, ls);
    }
    __builtin_amdgcn_s_setprio(0);
  };

  stage(0);
  stage(1);

  f32x16 sA[2], sB[2];

  for (int it = 0; it < nt; it += 2) {
    // ---- even sub-iter: QKT(it) -> sA ; finish(it-1) from sB ; stage(it+2) ----
    if (it < nt - 1) asm volatile("s_waitcnt vmcnt(4)" ::: "memory");
    else             asm volatile("s_waitcnt vmcnt(0)" ::: "memory");
    __builtin_amdgcn_s_barrier();
    __builtin_amdgcn_sched_barrier(0);
    {
      const int kv0 = 64 * it;
      if (kv0 <= qw + 31) qkt(sA, Ks[it & 3], kv0);
      if (it > 0 && kv0 - 64 <= qw + 31) finish(sB, Vs[(it - 1) & 3]);
      if (it + 2 < nt) stage((it + 2) & 3);
    }
    // ---- odd sub-iter: QKT(it+1) -> sB ; finish(it) from sA ; stage(it+3) ----
    const int it1 = it + 1;
    if (it1 < nt - 1) asm volatile("s_waitcnt vmcnt(4)" ::: "memory");
    else              asm volatile("s_waitcnt vmcnt(0)" ::: "memory");
    __builtin_amdgcn_s_barrier();
    __builtin_amdgcn_sched_barrier(0);
    {
      const int kv0 = 64 * it1;
      if (kv0 <= qw + 31) qkt(sB, Ks[it1 & 3], kv0);
      if (kv0 - 64 <= qw + 31) finish(sA, Vs[it & 3]);
      if (it1 + 2 < nt) stage((it1 + 2) & 3);
    }
  }
  // drain: finish last tile (nt-1, held in sB)
  if (64 * (nt - 1) <= qw + 31) finish(sB, Vs[(nt - 1) & 3]);

  // ---- epilogue: lane holds O^T[d = 32db+(r&3)+8(r>>2)+4hb][q = qw+l31] ----
  const float inv = 1.0f / ls[0];
  const int b = bh >> 4, h = bh & 15;
  const int q = qw + l31;
  unsigned short* cp = ctx + ((size_t)(b * 2048 + q) * 1024) + h * 64;
#pragma unroll
  for (int db = 0; db < 2; ++db)
#pragma unroll
    for (int i = 0; i < 8; ++i) {
      unsigned w = cvtpk(o[db][2 * i] * inv, o[db][2 * i + 1] * inv);
      int d = 32 * db + ((2 * i) & 3) + 8 * (i >> 1) + 4 * hb;
      *reinterpret_cast<unsigned*>(cp + d) = w;
    }
}

extern "C" void kernel_launch(void* const* d_in, const int* in_sizes, int n_in,
                              void* d_out, int out_size, void* d_ws, size_t ws_size,
                              hipStream_t stream) {
  const float* in_q = (const float*)d_in[0];
  const float* in_k = (const float*)d_in[1];
  const float* in_v = (const float*)d_in[2];
  const float* WQw = (const float*)d_in[3];
  const float* WQb = (const float*)d_in[4];
  const float* WKw = (const float*)d_in[5];
  const float* WKb = (const float*)d_in[6];
  const float* WVw = (const float*)d_in[7];
  const float* WVb = (const float*)d_in[8];
  const float* Ww  = (const float*)d_in[9];
  const float* Wb  = (const float*)d_in[10];
  float* out = (float*)d_out;

  constexpr size_t PROJ = (size_t)4 * 16 * 2048 * 64;  // 8,388,608 elems
  constexpr size_t WSZ = (size_t)1024 * 1024;
  const float qscale = 0.03125f * 1.4426950408889634f;  // 1/sqrt(1024) * log2(e)
  unsigned short* wsp = (unsigned short*)d_ws;

  const bool fused = ws_size >= (6 * PROJ + 4 * WSZ) * sizeof(unsigned short);

  if (fused) {
    unsigned short* Qp   = wsp;
    unsigned short* Kp   = wsp + PROJ;
    unsigned short* Vt   = wsp + 2 * PROJ;
    unsigned short* inq  = wsp + 3 * PROJ;  // later aliased as ctx
    unsigned short* ctx  = inq;
    unsigned short* ink  = wsp + 4 * PROJ;
    unsigned short* inv  = wsp + 5 * PROJ;
    unsigned short* wq16 = wsp + 6 * PROJ;
    unsigned short* wk16 = wq16 + WSZ;
    unsigned short* wv16 = wk16 + WSZ;
    unsigned short* ww16 = wv16 + WSZ;

    cvt_first_kernel<<<dim3(1024, 5), 256, 0, stream>>>(
        WQw, WKw, WVw, Ww, wq16, wk16, wv16, ww16, (int)(WSZ / 8),
        in_q, inq, (int)(PROJ / 8));
    gemm_kernel<0><<<2560, 256, 0, stream>>>(inq, wq16, WQb, Qp, 8192, 1024, 1024,
                                             qscale, 3, 512, in_k, ink, (int)(PROJ / 8));
    gemm_kernel<0><<<2560, 256, 0, stream>>>(ink, wk16, WKb, Kp, 8192, 1024, 1024,
                                             1.0f, 3, 512, in_v, inv, (int)(PROJ / 8));
    gemm_kernel<2><<<512, 256, 0, stream>>>(wv16, inv, WVb, Vt, 1024, 8192, 1024,
                                            1.0f, 6, 512, nullptr, nullptr, 0);
    attn10_kernel<<<1024, 256, 0, stream>>>(Qp, Kp, Vt, ctx);
    gemm_kernel<1><<<512, 256, 0, stream>>>(ctx, ww16, Wb, out, 8192, 1024, 1024,
                                            1.0f, 3, 512, nullptr, nullptr, 0);
  } else {
    unsigned short* Qp   = wsp;
    unsigned short* Kp   = wsp + PROJ;
    unsigned short* Vt   = wsp + 2 * PROJ;
    unsigned short* in16 = wsp + 3 * PROJ;
    unsigned short* ctx  = in16;
    unsigned short* wq16 = wsp + 4 * PROJ;
    unsigned short* wk16 = wq16 + WSZ;
    unsigned short* wv16 = wk16 + WSZ;
    unsigned short* ww16 = wv16 + WSZ;

    cvt_first_kernel<<<dim3(1024, 5), 256, 0, stream>>>(
        WQw, WKw, WVw, Ww, wq16, wk16, wv16, ww16, (int)(WSZ / 8),
        in_q, in16, (int)(PROJ / 8));
    gemm_kernel<0><<<512, 256, 0, stream>>>(in16, wq16, WQb, Qp, 8192, 1024, 1024,
                                            qscale, 3, 512, nullptr, nullptr, 0);
    cvt1_kernel<<<2048, 256, 0, stream>>>(in_k, in16, (int)(PROJ / 8));
    gemm_kernel<0><<<512, 256, 0, stream>>>(in16, wk16, WKb, Kp, 8192, 1024, 1024,
                                            1.0f, 3, 512, nullptr, nullptr, 0);
    cvt1_kernel<<<2048, 256, 0, stream>>>(in_v, in16, (int)(PROJ / 8));
    gemm_kernel<2><<<512, 256, 0, stream>>>(wv16, in16, WVb, Vt, 1024, 8192, 1024,
                                            1.0f, 6, 512, nullptr, nullptr, 0);
    attn10_kernel<<<1024, 256, 0, stream>>>(Qp, Kp, Vt, ctx);
    gemm_kernel<1><<<512, 256, 0, stream>>>(ctx, ww16, Wb, out, 8192, 1024, 1024,
                                            1.0f, 3, 512, nullptr, nullptr, 0);
  }
}